// Round 12
// baseline (99.331 us; speedup 1.0000x reference)
//
#include <hip/hip_runtime.h>
#include <math.h>

#define NUM_ENTITY 100000
#define NUM_TYPE   5000
#define DIM        128
#define BATCH      512
#define MARGIN     2.0f

#define TG 64       // types per block (one per lane)
#define BB 32       // batch rows per block (8 per wave)
#define BG 8        // batch rows per wave
#define TSTRIDE 68  // t-tile row stride in dwords (64+4; b128 row-reads = exact 2/bank min)

typedef _Float16 half_t;
typedef half_t half2_t __attribute__((ext_vector_type(2)));

// Synthesis of r7 (multi-wave staging amortization) + r11 (t-in-registers,
// e-broadcast compute). 4-wave block stages ONE t-tile (f16 [64][68]dw) +
// 32-row e-tile, one barrier; each wave then computes 8 b-rows against its
// lane's register-resident type row. t-stage redundancy 64x -> 16x.
// (256,2): 128-VGPR cap >= ~95 live-set (r8: harmless) keeps 6 blocks/CU
// (LDS 25.6KB) = 24 waves/CU. unroll 4 bounds ev-hoisting to 16 VGPR.
__device__ __forceinline__ uint32_t pk2(float x, float y) {
    return __builtin_bit_cast(uint32_t, __builtin_amdgcn_cvt_pkrtz(x, y));
}

__device__ __forceinline__ float absdot(uint32_t eu, uint32_t tu, float acc) {
    const half2_t ones = {(half_t)1.0f, (half_t)1.0f};
    half2_t d = __builtin_bit_cast(half2_t, eu) - __builtin_bit_cast(half2_t, tu);
    const uint32_t du = __builtin_bit_cast(uint32_t, d) & 0x7fff7fffu;
#if __has_builtin(__builtin_amdgcn_fdot2)
    return __builtin_amdgcn_fdot2(__builtin_bit_cast(half2_t, du), ones, acc, false);
#else
    half2_t a = __builtin_bit_cast(half2_t, du);
    return acc + (float)a[0] + (float)a[1];
#endif
}

__global__ __launch_bounds__(256, 2) void l1dist_sigmoid_kernel(
    const float* __restrict__ ent,
    const float* __restrict__ typ,
    const int*   __restrict__ xb,
    float*       __restrict__ out)
{
    __shared__ uint32_t tL[TG * TSTRIDE];   // 17408 B, packed f16
    __shared__ uint32_t eL[BB * 64];        //  8192 B, packed f16

    const int tid = threadIdx.x;            // 0..255
    const int l   = tid & 63;               // lane
    const int w   = tid >> 6;               // wave 0..3
    const int t0  = blockIdx.x * TG;
    const int b0  = blockIdx.y * BB;

    // ---- stage e tile: 32 rows x 32 float4 = 1024 f4, 4 per thread
#pragma unroll
    for (int s = 0; s < 4; ++s) {
        const int g   = tid + 256 * s;
        const int row = g >> 5;
        const int c4  = g & 31;
        const int er  = xb[b0 + row];
        const float4 v = *(const float4*)&ent[er * DIM + c4 * 4];
        uint2 pw;
        pw.x = pk2(v.x, v.y);
        pw.y = pk2(v.z, v.w);
        *(uint2*)&eL[row * 64 + c4 * 2] = pw;
    }

    // ---- stage t tile COALESCED: 64 rows x 32 float4 = 2048 f4, 8 per thread
#pragma unroll
    for (int s = 0; s < 8; ++s) {
        const int g   = tid + 256 * s;
        const int row = g >> 5;
        const int c4  = g & 31;
        const int tr  = min(t0 + row, NUM_TYPE - 1);
        const float4 v = *(const float4*)&typ[tr * DIM + c4 * 4];
        uint2 pw;
        pw.x = pk2(v.x, v.y);
        pw.y = pk2(v.z, v.w);
        *(uint2*)&tL[row * TSTRIDE + c4 * 2] = pw;
    }

    __syncthreads();

    // ---- own type row LDS -> registers (16 x ds_read_b128, 2/bank = free)
    uint4 tf[16];
#pragma unroll
    for (int c = 0; c < 16; ++c)
        tf[c] = *(const uint4*)&tL[l * TSTRIDE + c * 4];

    const bool valid = (t0 + l) < NUM_TYPE;
    const int  wb    = w * BG;   // this wave's first b-row in the tile

    // ---- compute: 8 b-rows per wave; e read as wave-uniform broadcast b128
#pragma unroll 1
    for (int i = 0; i < BG; ++i) {
        float acc = 0.0f;
#pragma unroll 4
        for (int c = 0; c < 16; ++c) {
            const uint4 ev = *(const uint4*)&eL[(wb + i) * 64 + c * 4];
            acc = absdot(ev.x, tf[c].x, acc);
            acc = absdot(ev.y, tf[c].y, acc);
            acc = absdot(ev.z, tf[c].z, acc);
            acc = absdot(ev.w, tf[c].w, acc);
        }
        if (valid) {
            const float x = MARGIN - acc;
            out[(b0 + wb + i) * NUM_TYPE + t0 + l] = 1.0f / (1.0f + __expf(-x));
        }
    }
}

extern "C" void kernel_launch(void* const* d_in, const int* in_sizes, int n_in,
                              void* d_out, int out_size, void* d_ws, size_t ws_size,
                              hipStream_t stream) {
    const float* ent = (const float*)d_in[0];
    const float* typ = (const float*)d_in[1];
    const int*   xb  = (const int*)d_in[2];
    float*       out = (float*)d_out;

    dim3 grid((NUM_TYPE + TG - 1) / TG, BATCH / BB);  // (79, 16) = 1264 blocks x 4 waves
    dim3 block(256);
    l1dist_sigmoid_kernel<<<grid, block, 0, stream>>>(ent, typ, xb, out);
}

// Round 13
// 26.071 us; speedup vs baseline: 3.8100x; 3.8100x over previous
//
#include <hip/hip_runtime.h>
#include <math.h>

#define NUM_ENTITY 100000
#define NUM_TYPE   5000
#define DIM        128
#define BATCH      512
#define MARGIN     2.0f

#define TG 64       // types per block (one per lane)
#define BB 32       // batch rows per block (8 per wave)
#define BG 8        // batch rows per wave
#define TSTRIDE 68  // t-tile row stride in dwords (64+4; b128 row-reads = exact 2/bank min)

typedef _Float16 half_t;
typedef half_t half2_t __attribute__((ext_vector_type(2)));

// r12 post-mortem: __launch_bounds__(256,2) drove the allocator to 40 VGPR
// (not "up to 128") and spilled tf -> 91 MB scratch writes, 99us. Session
// law (4 pts): min-waves 8/4/2 -> VGPR 32/64/40, ALL spill; only
// min-waves=1 or bare bounds give sane allocation (r3/r7/r11: 88, no spill).
// hipcc treats arg2 as an occupancy TARGET it serves aggressively, not a cap.
// This round: identical design, (256,1). Residency is LDS-capped at
// 6 blocks/CU (25.6 KB) either way, so nothing is lost.
__device__ __forceinline__ uint32_t pk2(float x, float y) {
    return __builtin_bit_cast(uint32_t, __builtin_amdgcn_cvt_pkrtz(x, y));
}

__device__ __forceinline__ float absdot(uint32_t eu, uint32_t tu, float acc) {
    const half2_t ones = {(half_t)1.0f, (half_t)1.0f};
    half2_t d = __builtin_bit_cast(half2_t, eu) - __builtin_bit_cast(half2_t, tu);
    const uint32_t du = __builtin_bit_cast(uint32_t, d) & 0x7fff7fffu;
#if __has_builtin(__builtin_amdgcn_fdot2)
    return __builtin_amdgcn_fdot2(__builtin_bit_cast(half2_t, du), ones, acc, false);
#else
    half2_t a = __builtin_bit_cast(half2_t, du);
    return acc + (float)a[0] + (float)a[1];
#endif
}

__global__ __launch_bounds__(256, 1) void l1dist_sigmoid_kernel(
    const float* __restrict__ ent,
    const float* __restrict__ typ,
    const int*   __restrict__ xb,
    float*       __restrict__ out)
{
    __shared__ uint32_t tL[TG * TSTRIDE];   // 17408 B, packed f16
    __shared__ uint32_t eL[BB * 64];        //  8192 B, packed f16

    const int tid = threadIdx.x;            // 0..255
    const int l   = tid & 63;               // lane
    const int w   = tid >> 6;               // wave 0..3
    const int t0  = blockIdx.x * TG;
    const int b0  = blockIdx.y * BB;

    // ---- stage e tile: 32 rows x 32 float4 = 1024 f4, 4 per thread
#pragma unroll
    for (int s = 0; s < 4; ++s) {
        const int g   = tid + 256 * s;
        const int row = g >> 5;
        const int c4  = g & 31;
        const int er  = xb[b0 + row];
        const float4 v = *(const float4*)&ent[er * DIM + c4 * 4];
        uint2 pw;
        pw.x = pk2(v.x, v.y);
        pw.y = pk2(v.z, v.w);
        *(uint2*)&eL[row * 64 + c4 * 2] = pw;
    }

    // ---- stage t tile COALESCED: 64 rows x 32 float4 = 2048 f4, 8 per thread
#pragma unroll
    for (int s = 0; s < 8; ++s) {
        const int g   = tid + 256 * s;
        const int row = g >> 5;
        const int c4  = g & 31;
        const int tr  = min(t0 + row, NUM_TYPE - 1);
        const float4 v = *(const float4*)&typ[tr * DIM + c4 * 4];
        uint2 pw;
        pw.x = pk2(v.x, v.y);
        pw.y = pk2(v.z, v.w);
        *(uint2*)&tL[row * TSTRIDE + c4 * 2] = pw;
    }

    __syncthreads();

    // ---- own type row LDS -> registers (16 x ds_read_b128, 2/bank = free)
    uint4 tf[16];
#pragma unroll
    for (int c = 0; c < 16; ++c)
        tf[c] = *(const uint4*)&tL[l * TSTRIDE + c * 4];

    const bool valid = (t0 + l) < NUM_TYPE;
    const int  wb    = w * BG;   // this wave's first b-row in the tile

    // ---- compute: 8 b-rows per wave; e read as wave-uniform broadcast b128
#pragma unroll 1
    for (int i = 0; i < BG; ++i) {
        float acc = 0.0f;
#pragma unroll
        for (int c = 0; c < 16; ++c) {
            const uint4 ev = *(const uint4*)&eL[(wb + i) * 64 + c * 4];
            acc = absdot(ev.x, tf[c].x, acc);
            acc = absdot(ev.y, tf[c].y, acc);
            acc = absdot(ev.z, tf[c].z, acc);
            acc = absdot(ev.w, tf[c].w, acc);
        }
        if (valid) {
            const float x = MARGIN - acc;
            out[(b0 + wb + i) * NUM_TYPE + t0 + l] = 1.0f / (1.0f + __expf(-x));
        }
    }
}

extern "C" void kernel_launch(void* const* d_in, const int* in_sizes, int n_in,
                              void* d_out, int out_size, void* d_ws, size_t ws_size,
                              hipStream_t stream) {
    const float* ent = (const float*)d_in[0];
    const float* typ = (const float*)d_in[1];
    const int*   xb  = (const int*)d_in[2];
    float*       out = (float*)d_out;

    dim3 grid((NUM_TYPE + TG - 1) / TG, BATCH / BB);  // (79, 16) = 1264 blocks x 4 waves
    dim3 block(256);
    l1dist_sigmoid_kernel<<<grid, block, 0, stream>>>(ent, typ, xb, out);
}